// Round 14
// baseline (121.331 us; speedup 1.0000x reference)
//
#include <hip/hip_runtime.h>

typedef _Float16 h2 __attribute__((ext_vector_type(2)));
typedef _Float16 h8 __attribute__((ext_vector_type(8)));
typedef float f32x4 __attribute__((ext_vector_type(4)));
typedef float f2 __attribute__((ext_vector_type(2)));

#define B_  16
#define Q_  1024
#define C_  256
#define HW_ 1024
#define TQA 64     // attn queries per block
#define NTA 512
#define QLD 264    // q_lds leading dim (halfwords): 256 + 8 pad
#define BT  256    // conv kernel threads
#define XRB 80     // bytes per padded ximg row (40 halfwords)
#define XIMGB (34 * XRB)   // 2720 B per padded image
#define HRB 576    // bytes per Hb row (36 slots * 16B, zero border)
#define HBIMG (34 * HRB)   // 19584 B per image H

__device__ __forceinline__ h2 u2h(unsigned u) { return __builtin_bit_cast(h2, u); }
__device__ __forceinline__ unsigned h2u(h2 h) { return __builtin_bit_cast(unsigned, h); }
__device__ __forceinline__ unsigned pkrtz(float a, float b) {
    return __builtin_bit_cast(unsigned, __builtin_amdgcn_cvt_pkrtz(a, b));
}

// ---------- prepass 1: keys f32 -> f16 ----------
__global__ void cvt_keys_f16(const float* __restrict__ src,
                             _Float16* __restrict__ dst, int n8) {
    int i = blockIdx.x * blockDim.x + threadIdx.x;
    if (i >= n8) return;
    const float4* s = (const float4*)src;
    float4 a = s[2 * i], b = s[2 * i + 1];
    h8 v;
    v[0] = (_Float16)a.x; v[1] = (_Float16)a.y; v[2] = (_Float16)a.z; v[3] = (_Float16)a.w;
    v[4] = (_Float16)b.x; v[5] = (_Float16)b.y; v[6] = (_Float16)b.z; v[7] = (_Float16)b.w;
    *(h8*)(dst + (size_t)i * 8) = v;
}

// ---------- prepass 2: pack conv weights as f32 channel-pairs ----------
// wpkf (f32): [0..71]   w1p[t][p] = (w1[2p][t], w1[2p+1][t])  at (t*4+p)*2
//             [72..79]  b1p[p]    at 72+2p
//             [80..151] w2p[t][p] at 80+(t*4+p)*2
//             [152]     b2
__global__ void pack_weights(const float* __restrict__ w1, const float* __restrict__ b1,
                             const float* __restrict__ w2, const float* __restrict__ b2,
                             float* __restrict__ wpkf) {
    int t = threadIdx.x;
    if (t < 36) {
        int tt = t >> 2, p = t & 3;
        wpkf[2 * t + 0] = w1[(2 * p) * 9 + tt];
        wpkf[2 * t + 1] = w1[(2 * p + 1) * 9 + tt];
    } else if (t < 40) {
        int p = t - 36;
        wpkf[72 + 2 * p + 0] = b1[2 * p];
        wpkf[72 + 2 * p + 1] = b1[2 * p + 1];
    } else if (t < 76) {
        int i = t - 40; int tt = i >> 2, p = i & 3;
        wpkf[80 + 2 * i + 0] = w2[(2 * p) * 9 + tt];
        wpkf[80 + 2 * i + 1] = w2[(2 * p + 1) * 9 + tt];
    } else if (t == 76) {
        wpkf[152] = b2[0];
    }
}

// ---------- kernel A: QK^T (f16 MFMA, TQ=64, 4 MFMA per B-load) + bias + softmax ----------
__global__ __launch_bounds__(NTA, 2) void attn_kernel(
    const float* __restrict__ queries, const _Float16* __restrict__ keysh,
    const int* __restrict__ pos, const float* __restrict__ rel_bias,
    _Float16* __restrict__ xmapg)
{
    __shared__ _Float16 q_lds[TQA * QLD];      // 33.8 KiB
    __shared__ _Float16 bias_lds[63 * 64];     // 8 KiB
    __shared__ float red_max[8][TQA];
    __shared__ float red_sum[8][TQA];
    __shared__ int2  pos_lds[TQA];

    const int tid = threadIdx.x;
    const int bid = blockIdx.x;
    const int swz = (bid & 7) * 32 + (bid >> 3);    // XCD-chunked (256 % 8 == 0)
    const int batch = swz >> 4;
    const int tile  = swz & 15;

    {
        const float4* qsrc = (const float4*)(queries + (size_t)(batch * Q_ + tile * TQA) * C_);
        #pragma unroll
        for (int i = 0; i < 8; ++i) {
            int e4 = i * NTA + tid;                 // 0..4095
            float4 v = qsrc[e4];
            int row = e4 >> 6, col4 = e4 & 63;
            _Float16* d = &q_lds[row * QLD + col4 * 4];
            d[0] = (_Float16)v.x; d[1] = (_Float16)v.y;
            d[2] = (_Float16)v.z; d[3] = (_Float16)v.w;
        }
        for (int idx = tid; idx < 63 * 63; idx += NTA) {
            int r = idx / 63;
            bias_lds[r * 64 + (idx - r * 63)] = (_Float16)rel_bias[idx];
        }
        if (tid < TQA)
            pos_lds[tid] = ((const int2*)pos)[batch * Q_ + tile * TQA + tid];
    }
    __syncthreads();

    const int lane = tid & 63;
    const int wv   = tid >> 6;          // 0..7 -> 128-col slice
    const int kgrp = (lane >> 4) * 8;
    const int l15  = lane & 15;
    const int rowbase = (lane >> 4) << 2;

    f32x4 acc[4][8];
    #pragma unroll
    for (int mt = 0; mt < 4; ++mt)
        #pragma unroll
        for (int f = 0; f < 8; ++f) acc[mt][f] = f32x4{0.f, 0.f, 0.f, 0.f};

    const _Float16* kb = keysh + (size_t)batch * (HW_ * C_)
                       + (size_t)(wv * 128 + l15) * C_ + kgrp;
    #pragma unroll
    for (int ks = 0; ks < 8; ++ks) {
        h8 a[4];
        #pragma unroll
        for (int mt = 0; mt < 4; ++mt)
            a[mt] = *(const h8*)&q_lds[(mt * 16 + l15) * QLD + ks * 32 + kgrp];
        #pragma unroll
        for (int f = 0; f < 8; ++f) {
            h8 bfr = *(const h8*)(kb + f * (16 * C_) + ks * 32);
            #pragma unroll
            for (int mt = 0; mt < 4; ++mt)
                acc[mt][f] = __builtin_amdgcn_mfma_f32_16x16x32_f16(a[mt], bfr, acc[mt][f], 0, 0, 0);
        }
    }
    // C/D: col = wv*128 + f*16 + l15, row = mt*16 + rowbase + r

    int p0r[4][4], p1r[4][4];
    #pragma unroll
    for (int mt = 0; mt < 4; ++mt)
        #pragma unroll
        for (int r = 0; r < 4; ++r) {
            int2 pp = pos_lds[mt * 16 + rowbase + r];
            p0r[mt][r] = pp.x; p1r[mt][r] = pp.y;
        }

    float mrow[4][4];
    #pragma unroll
    for (int mt = 0; mt < 4; ++mt)
        #pragma unroll
        for (int r = 0; r < 4; ++r) mrow[mt][r] = -3e38f;

    #pragma unroll
    for (int f = 0; f < 8; ++f) {
        int col = wv * 128 + f * 16 + l15;
        int hh = col >> 5, ww = col & 31;
        #pragma unroll
        for (int mt = 0; mt < 4; ++mt)
            #pragma unroll
            for (int r = 0; r < 4; ++r) {
                float s = acc[mt][f][r] * 0.0625f
                        + (float)bias_lds[(hh - p0r[mt][r] + 31) * 64 + (ww - p1r[mt][r] + 31)];
                acc[mt][f][r] = s;
                mrow[mt][r] = fmaxf(mrow[mt][r], s);
            }
    }
    #pragma unroll
    for (int mt = 0; mt < 4; ++mt)
        #pragma unroll
        for (int r = 0; r < 4; ++r) {
            float m = mrow[mt][r];
            m = fmaxf(m, __shfl_xor(m, 1, 64));
            m = fmaxf(m, __shfl_xor(m, 2, 64));
            m = fmaxf(m, __shfl_xor(m, 4, 64));
            m = fmaxf(m, __shfl_xor(m, 8, 64));
            mrow[mt][r] = m;
        }
    if (l15 == 0) {
        #pragma unroll
        for (int mt = 0; mt < 4; ++mt)
            #pragma unroll
            for (int r = 0; r < 4; ++r)
                red_max[wv][mt * 16 + rowbase + r] = mrow[mt][r];
    }
    __syncthreads();

    float sm[4][4];
    #pragma unroll
    for (int mt = 0; mt < 4; ++mt)
        #pragma unroll
        for (int r = 0; r < 4; ++r) {
            float m = red_max[0][mt * 16 + rowbase + r];
            #pragma unroll
            for (int w = 1; w < 8; ++w) m = fmaxf(m, red_max[w][mt * 16 + rowbase + r]);
            mrow[mt][r] = m;     // reuse as row max
            sm[mt][r] = 0.f;
        }

    #pragma unroll
    for (int f = 0; f < 8; ++f) {
        #pragma unroll
        for (int mt = 0; mt < 4; ++mt)
            #pragma unroll
            for (int r = 0; r < 4; ++r) {
                float e = __expf(acc[mt][f][r] - mrow[mt][r]);
                acc[mt][f][r] = e;
                sm[mt][r] += e;
            }
    }
    #pragma unroll
    for (int mt = 0; mt < 4; ++mt)
        #pragma unroll
        for (int r = 0; r < 4; ++r) {
            float s = sm[mt][r];
            s += __shfl_xor(s, 1, 64);
            s += __shfl_xor(s, 2, 64);
            s += __shfl_xor(s, 4, 64);
            s += __shfl_xor(s, 8, 64);
            sm[mt][r] = s;
        }
    if (l15 == 0) {
        #pragma unroll
        for (int mt = 0; mt < 4; ++mt)
            #pragma unroll
            for (int r = 0; r < 4; ++r)
                red_sum[wv][mt * 16 + rowbase + r] = sm[mt][r];
    }
    __syncthreads();

    _Float16* xg = xmapg + (size_t)(batch * Q_ + tile * TQA) * HW_;
    #pragma unroll
    for (int mt = 0; mt < 4; ++mt) {
        float sinv[4];
        #pragma unroll
        for (int r = 0; r < 4; ++r) {
            float S = red_sum[0][mt * 16 + rowbase + r];
            #pragma unroll
            for (int w = 1; w < 8; ++w) S += red_sum[w][mt * 16 + rowbase + r];
            sinv[r] = 1.0f / S;
        }
        #pragma unroll
        for (int f = 0; f < 8; ++f) {
            int col = wv * 128 + f * 16 + l15;
            #pragma unroll
            for (int r = 0; r < 4; ++r)
                xg[(size_t)(mt * 16 + rowbase + r) * HW_ + col]
                    = (_Float16)(acc[mt][f][r] * sinv[r]);
        }
    }
}

// ---------- kernel B: conv1/relu/conv2 + residual (8-px runs, packed-f32 math) ----------
__global__ __launch_bounds__(BT, 3) void conv_kernel(
    const _Float16* __restrict__ xmapg, const float* __restrict__ wpkf,
    float* __restrict__ out)
{
    __shared__ __align__(16) char xall[16 + 4 * XIMGB];   // 10896 B (guard + 4 padded images)
    __shared__ __align__(16) char Hb[2 * HBIMG];          // 39168 B (2 bordered H images)

    const int tid = threadIdx.x;
    const int bid = blockIdx.x;
    const int swz = (bid & 7) * 512 + (bid >> 3);    // XCD-chunked (4096 % 8 == 0)
    const size_t img0 = (size_t)swz * 4;

    // ---- zero-fill pads/borders, then barrier BEFORE staging ----
    {
        const uint4 z = uint4{0u, 0u, 0u, 0u};
        uint4* xz = (uint4*)xall;
        for (int i = tid; i < (int)sizeof(xall) / 16; i += BT) xz[i] = z;
        uint4* hz = (uint4*)Hb;
        for (int i = tid; i < (int)sizeof(Hb) / 16; i += BT) hz[i] = z;
    }
    __syncthreads();

    // ---- stage 4 images (rows at r+1, cols 0..31 of 40) ----
    #pragma unroll
    for (int i = 0; i < 2; ++i) {
        int c = i * BT + tid;            // 0..511 : 16B chunks
        int im = c >> 7, cc = c & 127, r = cc >> 2, q = cc & 3;
        uint4 v = *(const uint4*)(xmapg + img0 * HW_ + (size_t)im * HW_ + cc * 8);
        *(uint4*)(xall + 16 + im * XIMGB + (r + 1) * XRB + q * 16) = v;
    }

    // ---- weights: uniform f32 loads (s_load -> SGPR pairs) ----
    f2 w1v[9][4], b1v[4], w2v[9][4];
    #pragma unroll
    for (int t = 0; t < 9; ++t)
        #pragma unroll
        for (int p = 0; p < 4; ++p) {
            w1v[t][p] = f2{wpkf[(t * 4 + p) * 2], wpkf[(t * 4 + p) * 2 + 1]};
            w2v[t][p] = f2{wpkf[80 + (t * 4 + p) * 2], wpkf[80 + (t * 4 + p) * 2 + 1]};
        }
    #pragma unroll
    for (int p = 0; p < 4; ++p)
        b1v[p] = f2{wpkf[72 + 2 * p], wpkf[72 + 2 * p + 1]};
    const float b2r = wpkf[152];

    // thread -> (half-image, y, 8-px run)
    const int r4   = tid & 3;            // x0 = 8*r4
    const int y    = (tid >> 2) & 31;
    const int half = tid >> 7;           // 0/1: which of 2 concurrent images
    const int x0   = r4 << 3;

    // window rows for output row y: padded rows y, y+1, y+2 (image rows y-1..y+1)
    const char* const xrow0 = xall + 16 + y * XRB + x0 * 2;
    char* const hb = Hb + half * HBIMG;
    char* const hst = hb + (y + 1) * HRB;            // conv1 store row
    const char* const hrd = hb + y * HRB + r4 * 32;  // conv2 read base

    __syncthreads();   // staging complete

    #pragma unroll 1
    for (int pass = 0; pass < 2; ++pass) {
        const int img = pass * 2 + half;
        const char* xi = xrow0 + img * XIMGB;

        // --- gather + convert once: xf[dy][0..9] = v_{-1}..v_8 (f32) ---
        float xf[3][10];
        #pragma unroll
        for (int dy = 0; dy < 3; ++dy) {
            unsigned em = *(const unsigned*)(xi + dy * XRB - 4);   // (v-2, v-1)
            uint4 a07   = *(const uint4*)(xi + dy * XRB);          // v0..v7
            unsigned e8 = *(const unsigned*)(xi + dy * XRB + 16);  // (v8, v9)
            xf[dy][0] = (float)u2h(em)[1];
            xf[dy][1] = (float)u2h(a07.x)[0]; xf[dy][2] = (float)u2h(a07.x)[1];
            xf[dy][3] = (float)u2h(a07.y)[0]; xf[dy][4] = (float)u2h(a07.y)[1];
            xf[dy][5] = (float)u2h(a07.z)[0]; xf[dy][6] = (float)u2h(a07.z)[1];
            xf[dy][7] = (float)u2h(a07.w)[0]; xf[dy][8] = (float)u2h(a07.w)[1];
            xf[dy][9] = (float)u2h(e8)[0];
        }

        // --- conv1 (px pairs): packed-f32 channel-pair accumulation ---
        #pragma unroll
        for (int j2 = 0; j2 < 4; ++j2) {
            f2 accA[4], accB[4];
            #pragma unroll
            for (int p = 0; p < 4; ++p) { accA[p] = b1v[p]; accB[p] = b1v[p]; }
            #pragma unroll
            for (int dy = 0; dy < 3; ++dy) {
                const float* xr = xf[dy];
                f2 s0 = {xr[2 * j2 + 0], xr[2 * j2 + 0]};
                f2 s1 = {xr[2 * j2 + 1], xr[2 * j2 + 1]};
                f2 s2 = {xr[2 * j2 + 2], xr[2 * j2 + 2]};
                f2 s3 = {xr[2 * j2 + 3], xr[2 * j2 + 3]};
                #pragma unroll
                for (int p = 0; p < 4; ++p) {
                    accA[p] += s0 * w1v[dy * 3 + 0][p];
                    accA[p] += s1 * w1v[dy * 3 + 1][p];
                    accA[p] += s2 * w1v[dy * 3 + 2][p];
                    accB[p] += s1 * w1v[dy * 3 + 0][p];
                    accB[p] += s2 * w1v[dy * 3 + 1][p];
                    accB[p] += s3 * w1v[dy * 3 + 2][p];
                }
            }
            uint4 hvA, hvB;
            #pragma unroll
            for (int p = 0; p < 4; ++p) {
                ((unsigned*)&hvA)[p] = pkrtz(fmaxf(accA[p][0], 0.f), fmaxf(accA[p][1], 0.f));
                ((unsigned*)&hvB)[p] = pkrtz(fmaxf(accB[p][0], 0.f), fmaxf(accB[p][1], 0.f));
            }
            const int cpA = x0 + 2 * j2 + 1, cpB = cpA + 1;
            *(uint4*)(hst + ((cpA & 3) * 9 + (cpA >> 2)) * 16) = hvA;
            *(uint4*)(hst + ((cpB & 3) * 9 + (cpB >> 2)) * 16) = hvB;
        }
        __syncthreads();   // H image complete

        // --- conv2 + residual (unguarded; zero border; slots g(c)=(c&3)*9+(c>>2)) ---
        f2 a2[8];
        #pragma unroll
        for (int j = 0; j < 8; ++j) a2[j] = f2{0.f, 0.f};
        #pragma unroll
        for (int dy = 0; dy < 3; ++dy) {
            const char* rb = hrd + dy * HRB;
            uint4 Hv[10];
            Hv[0] = *(const uint4*)(rb + 0);    Hv[1] = *(const uint4*)(rb + 144);
            Hv[2] = *(const uint4*)(rb + 288);  Hv[3] = *(const uint4*)(rb + 432);
            Hv[4] = *(const uint4*)(rb + 16);   Hv[5] = *(const uint4*)(rb + 160);
            Hv[6] = *(const uint4*)(rb + 304);  Hv[7] = *(const uint4*)(rb + 448);
            Hv[8] = *(const uint4*)(rb + 32);   Hv[9] = *(const uint4*)(rb + 176);
            #pragma unroll
            for (int k = 0; k < 10; ++k) {
                #pragma unroll
                for (int p = 0; p < 4; ++p) {
                    h2 hv = u2h(((const unsigned*)&Hv[k])[p]);
                    f2 hf = {(float)hv[0], (float)hv[1]};
                    #pragma unroll
                    for (int dx = 0; dx < 3; ++dx) {
                        const int j = k - dx;                  // px using slot k at tap dx
                        if (j >= 0 && j < 8)
                            a2[j] += hf * w2v[dy * 3 + dx][p];
                    }
                }
            }
        }
        {
            float o[8];
            #pragma unroll
            for (int j = 0; j < 8; ++j)
                o[j] = xf[1][j + 1] + a2[j][0] + a2[j][1] + b2r;
            float* op = out + (img0 + img) * HW_ + y * 32 + x0;
            *(float4*)(op)     = float4{o[0], o[1], o[2], o[3]};
            *(float4*)(op + 4) = float4{o[4], o[5], o[6], o[7]};
        }
        __syncthreads();   // readers done before next pass overwrites Hb
    }
}

extern "C" void kernel_launch(void* const* d_in, const int* in_sizes, int n_in,
                              void* d_out, int out_size, void* d_ws, size_t ws_size,
                              hipStream_t stream) {
    const float* queries  = (const float*)d_in[0];
    const float* keys     = (const float*)d_in[1];
    const int*   pos      = (const int*)d_in[2];
    const float* rel_bias = (const float*)d_in[3];
    const float* w1       = (const float*)d_in[4];
    const float* b1       = (const float*)d_in[5];
    const float* w2       = (const float*)d_in[6];
    const float* b2       = (const float*)d_in[7];
    float* out = (float*)d_out;

    float*     wpkf  = (float*)d_ws;                                     // 4 KiB slot
    _Float16*  keysh = (_Float16*)((char*)d_ws + 4096);                  // 8 MiB
    _Float16*  xmapg = (_Float16*)((char*)d_ws + 4096 + 8388608);        // 32 MiB

    const int n8 = (B_ * HW_ * C_) / 8;  // 524288
    pack_weights<<<dim3(1), dim3(128), 0, stream>>>(w1, b1, w2, b2, wpkf);
    cvt_keys_f16<<<dim3(n8 / 256), dim3(256), 0, stream>>>(keys, keysh, n8);
    attn_kernel<<<dim3(B_ * (Q_ / TQA)), dim3(NTA), 0, stream>>>(
        queries, keysh, pos, rel_bias, xmapg);
    conv_kernel<<<dim3((B_ * Q_) / 4), dim3(BT), 0, stream>>>(xmapg, wpkf, out);
}